// Round 12
// baseline (537.231 us; speedup 1.0000x reference)
//
#include <hip/hip_runtime.h>

typedef __attribute__((ext_vector_type(8))) unsigned short us8;
typedef __attribute__((ext_vector_type(8))) short s8;
typedef __attribute__((ext_vector_type(4))) float f4;
typedef __attribute__((ext_vector_type(2))) float f2;

#define DEV static __device__ __forceinline__
#define CAP 128
#define NRG 128    // dst ranges (one pass-2 block per range)
#define NBB 256    // bucketing blocks
#define SEGC 128   // per (range,block) segment capacity

DEV float bf2f(unsigned short h){ return __uint_as_float(((unsigned)h)<<16); }
DEV unsigned short f2bf(float f){
  unsigned x = __float_as_uint(f);
  x += 0x7fffu + ((x>>16)&1u);
  return (unsigned short)(x>>16);
}
DEV float sigm(float x){ return 1.f/(1.f + __expf(-x)); }

// ---------------- setup kernels ----------------
__global__ __launch_bounds__(256) void k_bucket(const int* __restrict__ src,
    const int* __restrict__ dst, unsigned* __restrict__ buf,
    int* __restrict__ cnt2, int e, int n){
  __shared__ int lcnt[NRG];
  int b = blockIdx.x;
  for(int i=threadIdx.x;i<NRG;i+=256) lcnt[i] = 0;
  __syncthreads();
  int chunk = (e + NBB - 1)/NBB;
  int lo = b*chunk;
  int hi = lo + chunk; if(hi>e) hi=e;
  for(int i = lo + threadIdx.x; i < hi; i += 256){
    int d = dst[i], s = src[i];
    int r = (d*NRG)/n;
    int pos = atomicAdd(&lcnt[r], 1);
    if(pos < SEGC)
      buf[((size_t)r*NBB + b)*SEGC + pos] = ((unsigned)d<<16) | (unsigned)s;
  }
  __syncthreads();
  for(int i=threadIdx.x;i<NRG;i+=256) cnt2[i*NBB + b] = lcnt[i];
}

__global__ __launch_bounds__(256) void k_build2(const unsigned* __restrict__ buf,
    const int* __restrict__ cnt2, int* __restrict__ cnt,
    unsigned short* __restrict__ col, int n){
  int r = blockIdx.x;
  int lo = (r*n + NRG-1)/NRG;
  int hi = ((r+1)*n + NRG-1)/NRG;   // exclusive
  int span = hi - lo;
  __shared__ int lc[512];
  for(int i=threadIdx.x; i<span; i+=256) lc[i] = 0;
  __syncthreads();
  int lane = threadIdx.x & 63;
  for(int seg = threadIdx.x>>6; seg < NBB; seg += 4){
    int c = cnt2[r*NBB + seg]; if(c > SEGC) c = SEGC;
    const unsigned* p = buf + ((size_t)r*NBB + seg)*SEGC;
    for(int i = lane; i < c; i += 64){
      unsigned v = p[i];
      int d = (int)(v >> 16), s = (int)(v & 0xffffu);
      int slot = atomicAdd(&lc[d - lo], 1);
      col[(size_t)d*CAP + slot] = (unsigned short)s;
    }
  }
  __syncthreads();
  for(int i=threadIdx.x; i<span; i+=256) cnt[lo + i] = lc[i];
}

__global__ void k_setup(const int* __restrict__ cnt, float* __restrict__ dinv, int n,
                        const float* __restrict__ Wx, const float* __restrict__ Wh,
                        unsigned short* __restrict__ WT){
  int gN = (n + 255)/256;
  int b = blockIdx.x;
  if(b < gN){
    int i = b*256 + threadIdx.x;
    if(i<n) dinv[i] = rsqrtf((float)cnt[i] + 1.0f);
  } else {
    int i = (b-gN)*256 + threadIdx.x;   // < 12*16384
    int m = i >> 14;
    int rem = i & 16383;
    int j = rem >> 7;
    int k = rem & 127;
    const float* W = (m<6) ? (Wx + (size_t)m*16384) : (Wh + (size_t)(m-6)*16384);
    WT[(size_t)m*16384 + rem] = f2bf(W[(size_t)k*128 + j]);
  }
}

// ---------------- per-layer kernels ----------------
template<int FULL>
__global__ void k_scale2(const float* __restrict__ inp, const float* __restrict__ hl,
                         const float* __restrict__ dinv, unsigned char* __restrict__ y2, int n){
  int i = blockIdx.x*blockDim.x+threadIdx.x;
  if(i >= n*32) return;
  int node = i>>5, d0 = (i&31)*4;
  float dv = dinv[node];
  f4 b = *(const f4*)(hl  + (size_t)node*128 + d0);
  unsigned pb = __builtin_amdgcn_cvt_pk_fp8_f32(dv*b[0], dv*b[1], 0, false);
  pb = __builtin_amdgcn_cvt_pk_fp8_f32(dv*b[2], dv*b[3], pb, true);
  *(unsigned*)(y2 + (size_t)node*256 + 128 + d0) = pb;
  if constexpr(FULL){
    f4 a = *(const f4*)(inp + (size_t)node*128 + d0);
    unsigned pa = __builtin_amdgcn_cvt_pk_fp8_f32(dv*a[0], dv*a[1], 0, false);
    pa = __builtin_amdgcn_cvt_pk_fp8_f32(dv*a[2], dv*a[3], pa, true);
    *(unsigned*)(y2 + (size_t)node*256 + d0) = pa;
  }
}

// CSR aggregation over fp8 rows (unchanged from R11)
template<int DB>
__global__ __launch_bounds__(256) void k_agg(const unsigned char* __restrict__ y,
    const int* __restrict__ cnt, const unsigned short* __restrict__ col,
    const float* __restrict__ dinv, unsigned short* __restrict__ out0,
    unsigned short* __restrict__ out1, int n)
{
  constexpr int GL = DB/16;
  constexpr int NG = 64/GL;
  constexpr int U = 8;
  int tid = threadIdx.x;
  int wave = tid>>6, lane = tid&63;
  int g = lane/GL, gl = lane%GL;
  int node = blockIdx.x*(4*NG) + wave*NG + g;
  if(node >= n) return;
  const unsigned char* yb = y + (size_t)gl*16;
  float acc[16];
  {
    uint4 q = *(const uint4*)(yb + (size_t)node*DB);
    const unsigned* qw = (const unsigned*)&q;
    #pragma unroll
    for(int w=0;w<4;++w){
      f2 lo = __builtin_amdgcn_cvt_pk_f32_fp8(qw[w], false);
      f2 hi = __builtin_amdgcn_cvt_pk_f32_fp8(qw[w], true);
      acc[w*4+0]=lo[0]; acc[w*4+1]=lo[1]; acc[w*4+2]=hi[0]; acc[w*4+3]=hi[1];
    }
  }
  const unsigned short* myrow = col + (size_t)node*CAP;
  int c_ = cnt[node];
  int last = c_ - 1;
  for(int i=0; i<c_; i += U){
    int s[U];
    #pragma unroll
    for(int u=0;u<U;++u){
      int ii = i + u; ii = (ii < last) ? ii : last;
      s[u] = myrow[ii];
    }
    uint4 v[U];
    #pragma unroll
    for(int u=0;u<U;++u) v[u] = *(const uint4*)(yb + (size_t)s[u]*DB);
    #pragma unroll
    for(int u=0;u<U;++u){
      if(i + u < c_){
        const unsigned* qw = (const unsigned*)&v[u];
        #pragma unroll
        for(int w=0;w<4;++w){
          f2 lo = __builtin_amdgcn_cvt_pk_f32_fp8(qw[w], false);
          f2 hi = __builtin_amdgcn_cvt_pk_f32_fp8(qw[w], true);
          acc[w*4+0]+=lo[0]; acc[w*4+1]+=lo[1]; acc[w*4+2]+=hi[0]; acc[w*4+3]+=hi[1];
        }
      }
    }
  }
  float dv = dinv[node];
  us8 w0, w1;
  #pragma unroll
  for(int j=0;j<8;++j){ w0[j]=f2bf(acc[j]*dv); w1[j]=f2bf(acc[8+j]*dv); }
  int c = gl*16;
  if constexpr(DB==128){
    *(us8*)(out0 + (size_t)node*128 + c)     = w0;
    *(us8*)(out0 + (size_t)node*128 + c + 8) = w1;
  } else {
    unsigned short* o = (c<128) ? (out0 + (size_t)node*128 + c)
                                : (out1 + (size_t)node*128 + (c-128));
    *(us8*)o = w0;
    *(us8*)(o+8) = w1;
  }
}

// ---- direct-global MFMA fragment loads (no LDS, no syncthreads) ----
DEV s8 ldA(const unsigned short* A, int row, int koff, int nrows){
  if(row < nrows) return *(const s8*)(A + (size_t)row*128 + koff);
  return (s8)(short)0;
}
DEV s8 ldB(const unsigned short* B, int j, int koff){
  return *(const s8*)(B + (size_t)j*128 + koff);
}

// ZH: Zb[:,0:128]=bf16(ax@Wxz+ah@Whz), Zb[:,128:256]=bf16(ax@Wxh)
// 64-row tiles, wave = 16 rows x 256 cols.
__global__ __launch_bounds__(256) void k_gzh(const unsigned short* __restrict__ ax,
    const unsigned short* __restrict__ ah, const unsigned short* __restrict__ Wxz,
    const unsigned short* __restrict__ Whz, const unsigned short* __restrict__ Wxh,
    unsigned short* __restrict__ Zb, int nrows)
{
  const int t = threadIdx.x, lane = t & 63, lo = lane & 15, hi = lane >> 4;
  const int r0 = blockIdx.x*64 + (t>>6)*16;
  const int arow = r0 + lo;
  f4 acc[16];
  #pragma unroll
  for(int n=0;n<16;++n) acc[n] = (f4)0.f;
  #pragma unroll
  for(int kk=0;kk<4;++kk){
    int koff = kk*32 + hi*8;
    s8 a0 = ldA(ax, arow, koff, nrows);
    #pragma unroll
    for(int n=0;n<16;++n){
      s8 b = ldB((n<8)?Wxz:Wxh, (n&7)*16+lo, koff);
      acc[n] = __builtin_amdgcn_mfma_f32_16x16x32_bf16(a0, b, acc[n], 0,0,0);
    }
  }
  #pragma unroll
  for(int kk=0;kk<4;++kk){
    int koff = kk*32 + hi*8;
    s8 a1 = ldA(ah, arow, koff, nrows);
    #pragma unroll
    for(int n=0;n<8;++n){
      s8 b = ldB(Whz, n*16+lo, koff);
      acc[n] = __builtin_amdgcn_mfma_f32_16x16x32_bf16(a1, b, acc[n], 0,0,0);
    }
  }
  #pragma unroll
  for(int n=0;n<16;++n){
    int colv = n*16 + lo;   // 0..255 maps z|h halves contiguously
    #pragma unroll
    for(int tt=0;tt<4;++tt){
      int row = r0 + hi*4 + tt;
      if(row < nrows) Zb[(size_t)row*256 + colv] = f2bf(acc[n][tt]);
    }
  }
}

// R: yq = fp8( dinv * sigm(ax@Wxr + ah@Whr + bxr+bhr) * hl )
__global__ __launch_bounds__(256) void k_gr(const unsigned short* __restrict__ ax,
    const unsigned short* __restrict__ ah, const unsigned short* __restrict__ Wxr,
    const unsigned short* __restrict__ Whr, const float* __restrict__ hl,
    const float* __restrict__ dinv, const float* __restrict__ b1,
    const float* __restrict__ b2, unsigned char* __restrict__ yq, int nrows)
{
  const int t = threadIdx.x, lane = t & 63, lo = lane & 15, hi = lane >> 4;
  const int r0 = blockIdx.x*64 + (t>>6)*16;
  const int arow = r0 + lo;
  f4 acc[8];
  #pragma unroll
  for(int n=0;n<8;++n) acc[n] = (f4)0.f;
  #pragma unroll
  for(int kk=0;kk<4;++kk){
    int koff = kk*32 + hi*8;
    s8 a0 = ldA(ax, arow, koff, nrows);
    #pragma unroll
    for(int n=0;n<8;++n){
      s8 b = ldB(Wxr, n*16+lo, koff);
      acc[n] = __builtin_amdgcn_mfma_f32_16x16x32_bf16(a0, b, acc[n], 0,0,0);
    }
  }
  #pragma unroll
  for(int kk=0;kk<4;++kk){
    int koff = kk*32 + hi*8;
    s8 a1 = ldA(ah, arow, koff, nrows);
    #pragma unroll
    for(int n=0;n<8;++n){
      s8 b = ldB(Whr, n*16+lo, koff);
      acc[n] = __builtin_amdgcn_mfma_f32_16x16x32_bf16(a1, b, acc[n], 0,0,0);
    }
  }
  #pragma unroll
  for(int n=0;n<8;++n){
    int colv = n*16 + lo;
    float bz = b1[colv] + b2[colv];
    #pragma unroll
    for(int tt=0;tt<4;++tt){
      int row = r0 + hi*4 + tt;
      if(row < nrows){
        float r = sigm(acc[n][tt] + bz);
        float q = dinv[row] * r * hl[(size_t)row*128 + colv];
        unsigned pk = __builtin_amdgcn_cvt_pk_fp8_f32(q, q, 0, false);
        yq[(size_t)row*128 + colv] = (unsigned char)(pk & 0xff);
      }
    }
  }
}

// Final: z = sigm(Zb[:,0:128]+bz); ht = tanh(aq@Whh + Zb[:,128:256]+bh)
// out = z*hl + (1-z)*ht;  optional y2out x-half = fp8(dinv*out)
__global__ __launch_bounds__(256) void k_gf(const unsigned short* __restrict__ aq,
    const unsigned short* __restrict__ Whh, const unsigned short* __restrict__ Zb,
    const float* __restrict__ hl, const float* __restrict__ dinv,
    const float* __restrict__ b1, const float* __restrict__ b2,
    const float* __restrict__ b3, const float* __restrict__ b4,
    float* __restrict__ outp, unsigned char* __restrict__ y2out, int nrows)
{
  const int t = threadIdx.x, lane = t & 63, lo = lane & 15, hi = lane >> 4;
  const int r0 = blockIdx.x*64 + (t>>6)*16;
  const int arow = r0 + lo;
  f4 acc[8];
  #pragma unroll
  for(int n=0;n<8;++n) acc[n] = (f4)0.f;
  #pragma unroll
  for(int kk=0;kk<4;++kk){
    int koff = kk*32 + hi*8;
    s8 a0 = ldA(aq, arow, koff, nrows);
    #pragma unroll
    for(int n=0;n<8;++n){
      s8 b = ldB(Whh, n*16+lo, koff);
      acc[n] = __builtin_amdgcn_mfma_f32_16x16x32_bf16(a0, b, acc[n], 0,0,0);
    }
  }
  #pragma unroll
  for(int n=0;n<8;++n){
    int colv = n*16 + lo;
    float bz = b1[colv] + b2[colv];
    float bh = b3[colv] + b4[colv];
    #pragma unroll
    for(int tt=0;tt<4;++tt){
      int row = r0 + hi*4 + tt;
      if(row < nrows){
        float z  = sigm(bf2f(Zb[(size_t)row*256 + colv]) + bz);
        float ht = tanhf(acc[n][tt] + bf2f(Zb[(size_t)row*256 + 128 + colv]) + bh);
        float ov = z*hl[(size_t)row*128 + colv] + (1.f - z)*ht;
        outp[(size_t)row*128 + colv] = ov;
        if(y2out){
          float q = dinv[row] * ov;
          unsigned pk = __builtin_amdgcn_cvt_pk_fp8_f32(q, q, 0, false);
          y2out[(size_t)row*256 + colv] = (unsigned char)(pk & 0xff);
        }
      }
    }
  }
}

extern "C" void kernel_launch(void* const* d_in, const int* in_sizes, int n_in,
                              void* d_out, int out_size, void* d_ws, size_t ws_size,
                              hipStream_t stream){
  const float* x  = (const float*)d_in[0];
  const int*   ei = (const int*)d_in[1];
  const float* h  = (const float*)d_in[2];
  const float* Wx = (const float*)d_in[3];
  const float* bx = (const float*)d_in[4];
  const float* Wh = (const float*)d_in[5];
  const float* bh = (const float*)d_in[6];
  float* out = (float*)d_out;

  const int N = in_sizes[0] / 128;
  const int E = in_sizes[1] / 2;
  const int L = in_sizes[2] / in_sizes[0];
  const int* src = ei;
  const int* dst = ei + E;

  char* w = (char*)d_ws;
  auto alloc = [&](size_t b)->char*{ char* p = w; w += (b + 255) & ~(size_t)255; return p; };
  int* cnt = (int*)alloc((size_t)N*sizeof(int));
  unsigned short* col = (unsigned short*)alloc((size_t)N*CAP*sizeof(short));
  float* dinv = (float*)alloc((size_t)N*sizeof(float));
  unsigned short* WT = (unsigned short*)alloc((size_t)12*16384*sizeof(short));
  unsigned char* y2 = (unsigned char*)alloc((size_t)N*256);
  unsigned short* ax = (unsigned short*)alloc((size_t)N*128*sizeof(short));
  unsigned short* ah = (unsigned short*)alloc((size_t)N*128*sizeof(short));
  unsigned char* yq = (unsigned char*)alloc((size_t)N*128);
  unsigned short* aq = (unsigned short*)alloc((size_t)N*128*sizeof(short));
  unsigned short* Zb = (unsigned short*)alloc((size_t)N*256*sizeof(short));
  unsigned* ebuf = (unsigned*)alloc((size_t)NRG*NBB*SEGC*sizeof(unsigned));
  int* cnt2 = (int*)alloc((size_t)NRG*NBB*sizeof(int));

  const int gN = (N + 255)/256;
  const int gew = (N*32 + 255)/256;
  const int g64 = (N + 63)/64;
  const int gagg4 = (N + 15)/16;
  const int gagg2 = (N + 31)/32;

  k_bucket<<<NBB,256,0,stream>>>(src, dst, ebuf, cnt2, E, N);
  k_build2<<<NRG,256,0,stream>>>(ebuf, cnt2, cnt, col, N);
  k_setup<<<gN + 768,256,0,stream>>>(cnt, dinv, N, Wx, Wh, WT);

  for(int l=0; l<L; ++l){
    const float* inp = (l==0) ? x : (out + (size_t)(l-1)*N*128);
    const float* hl  = h + (size_t)l*N*128;
    const float* bxz = bx + (size_t)(l*3+0)*128; const float* bhz = bh + (size_t)(l*3+0)*128;
    const float* bxr = bx + (size_t)(l*3+1)*128; const float* bhr = bh + (size_t)(l*3+1)*128;
    const float* bxh = bx + (size_t)(l*3+2)*128; const float* bhh = bh + (size_t)(l*3+2)*128;
    const unsigned short* Wxz = WT + (size_t)(l*3+0)*16384;
    const unsigned short* Wxr = WT + (size_t)(l*3+1)*16384;
    const unsigned short* Wxh = WT + (size_t)(l*3+2)*16384;
    const unsigned short* Whz = WT + (size_t)(6+l*3+0)*16384;
    const unsigned short* Whr = WT + (size_t)(6+l*3+1)*16384;
    const unsigned short* Whh = WT + (size_t)(6+l*3+2)*16384;

    if(l==0) k_scale2<1><<<gew,256,0,stream>>>(inp, hl, dinv, y2, N);
    else     k_scale2<0><<<gew,256,0,stream>>>(inp, hl, dinv, y2, N);
    k_agg<256><<<gagg4,256,0,stream>>>(y2, cnt, col, dinv, ax, ah, N);
    k_gzh<<<g64,256,0,stream>>>(ax, ah, Wxz, Whz, Wxh, Zb, N);
    k_gr<<<g64,256,0,stream>>>(ax, ah, Wxr, Whr, hl, dinv, bxr, bhr, yq, N);
    k_agg<128><<<gagg2,256,0,stream>>>(yq, cnt, col, dinv, aq, nullptr, N);
    k_gf<<<g64,256,0,stream>>>(aq, Whh, Zb, hl, dinv, bxz, bhz, bxh, bhh,
                               out + (size_t)l*N*128, (l+1<L) ? y2 : nullptr, N);
  }
}

// Round 13
// 407.804 us; speedup vs baseline: 1.3174x; 1.3174x over previous
//
#include <hip/hip_runtime.h>

typedef __attribute__((ext_vector_type(8))) unsigned short us8;
typedef __attribute__((ext_vector_type(8))) short s8;
typedef __attribute__((ext_vector_type(4))) float f4;
typedef __attribute__((ext_vector_type(2))) float f2;

#define DEV static __device__ __forceinline__
#define CAP 128
#define NRG 128    // dst ranges (one pass-2 block per range)
#define NBB 256    // bucketing blocks
#define SEGC 128   // per (range,block) segment capacity

DEV float bf2f(unsigned short h){ return __uint_as_float(((unsigned)h)<<16); }
DEV unsigned short f2bf(float f){
  unsigned x = __float_as_uint(f);
  x += 0x7fffu + ((x>>16)&1u);
  return (unsigned short)(x>>16);
}
DEV float sigm(float x){ return 1.f/(1.f + __expf(-x)); }

// ---------------- setup kernels ----------------
__global__ __launch_bounds__(256) void k_bucket(const int* __restrict__ src,
    const int* __restrict__ dst, unsigned* __restrict__ buf,
    int* __restrict__ cnt2, int e, int n){
  __shared__ int lcnt[NRG];
  int b = blockIdx.x;
  for(int i=threadIdx.x;i<NRG;i+=256) lcnt[i] = 0;
  __syncthreads();
  int chunk = (e + NBB - 1)/NBB;
  int lo = b*chunk;
  int hi = lo + chunk; if(hi>e) hi=e;
  for(int i = lo + threadIdx.x; i < hi; i += 256){
    int d = dst[i], s = src[i];
    int r = (d*NRG)/n;
    int pos = atomicAdd(&lcnt[r], 1);
    if(pos < SEGC)
      buf[((size_t)r*NBB + b)*SEGC + pos] = ((unsigned)d<<16) | (unsigned)s;
  }
  __syncthreads();
  for(int i=threadIdx.x;i<NRG;i+=256) cnt2[i*NBB + b] = lcnt[i];
}

__global__ __launch_bounds__(256) void k_build2(const unsigned* __restrict__ buf,
    const int* __restrict__ cnt2, int* __restrict__ cnt,
    unsigned short* __restrict__ col, int n){
  int r = blockIdx.x;
  int lo = (r*n + NRG-1)/NRG;
  int hi = ((r+1)*n + NRG-1)/NRG;
  int span = hi - lo;
  __shared__ int lc[512];
  for(int i=threadIdx.x; i<span; i+=256) lc[i] = 0;
  __syncthreads();
  int lane = threadIdx.x & 63;
  for(int seg = threadIdx.x>>6; seg < NBB; seg += 4){
    int c = cnt2[r*NBB + seg]; if(c > SEGC) c = SEGC;
    const unsigned* p = buf + ((size_t)r*NBB + seg)*SEGC;
    for(int i = lane; i < c; i += 64){
      unsigned v = p[i];
      int d = (int)(v >> 16), s = (int)(v & 0xffffu);
      int slot = atomicAdd(&lc[d - lo], 1);
      col[(size_t)d*CAP + slot] = (unsigned short)s;
    }
  }
  __syncthreads();
  for(int i=threadIdx.x; i<span; i+=256) cnt[lo + i] = lc[i];
}

// dinv + concatenated weight prep: WT[m][j][k] (m = l*3+g, j out-col, k 0..255)
// k<128 -> Wx[l][g][k][j], k>=128 -> Wh[l][g][k-128][j]
__global__ void k_setup(const int* __restrict__ cnt, float* __restrict__ dinv, int n,
                        const float* __restrict__ Wx, const float* __restrict__ Wh,
                        unsigned short* __restrict__ WT){
  int gN = (n + 255)/256;
  int b = blockIdx.x;
  if(b < gN){
    int i = b*256 + threadIdx.x;
    if(i<n) dinv[i] = rsqrtf((float)cnt[i] + 1.0f);
  } else {
    int i = (b-gN)*256 + threadIdx.x;   // < 6*32768
    int m = i >> 15;
    int rem = i & 32767;
    int j = rem >> 8;
    int k = rem & 255;
    float v = (k<128) ? Wx[((size_t)m*128 + k)*128 + j]
                      : Wh[((size_t)m*128 + (k-128))*128 + j];
    WT[(size_t)m*32768 + j*256 + k] = f2bf(v);
  }
}

// ---------------- per-layer kernels ----------------
template<int FULL>
__global__ void k_scale2(const float* __restrict__ inp, const float* __restrict__ hl,
                         const float* __restrict__ dinv, unsigned char* __restrict__ y2, int n){
  int i = blockIdx.x*blockDim.x+threadIdx.x;
  if(i >= n*32) return;
  int node = i>>5, d0 = (i&31)*4;
  float dv = dinv[node];
  f4 b = *(const f4*)(hl  + (size_t)node*128 + d0);
  unsigned pb = __builtin_amdgcn_cvt_pk_fp8_f32(dv*b[0], dv*b[1], 0, false);
  pb = __builtin_amdgcn_cvt_pk_fp8_f32(dv*b[2], dv*b[3], pb, true);
  *(unsigned*)(y2 + (size_t)node*256 + 128 + d0) = pb;
  if constexpr(FULL){
    f4 a = *(const f4*)(inp + (size_t)node*128 + d0);
    unsigned pa = __builtin_amdgcn_cvt_pk_fp8_f32(dv*a[0], dv*a[1], 0, false);
    pa = __builtin_amdgcn_cvt_pk_fp8_f32(dv*a[2], dv*a[3], pa, true);
    *(unsigned*)(y2 + (size_t)node*256 + d0) = pa;
  }
}

// CSR aggregation over fp8 rows; output bf16 [n][DB] (DB=256 -> axah, 128 -> aq)
template<int DB>
__global__ __launch_bounds__(256) void k_agg(const unsigned char* __restrict__ y,
    const int* __restrict__ cnt, const unsigned short* __restrict__ col,
    const float* __restrict__ dinv, unsigned short* __restrict__ out0, int n)
{
  constexpr int GL = DB/16;
  constexpr int NG = 64/GL;
  constexpr int U = 8;
  int tid = threadIdx.x;
  int wave = tid>>6, lane = tid&63;
  int g = lane/GL, gl = lane%GL;
  int node = blockIdx.x*(4*NG) + wave*NG + g;
  if(node >= n) return;
  const unsigned char* yb = y + (size_t)gl*16;
  float acc[16];
  {
    uint4 q = *(const uint4*)(yb + (size_t)node*DB);
    const unsigned* qw = (const unsigned*)&q;
    #pragma unroll
    for(int w=0;w<4;++w){
      f2 lo = __builtin_amdgcn_cvt_pk_f32_fp8(qw[w], false);
      f2 hi = __builtin_amdgcn_cvt_pk_f32_fp8(qw[w], true);
      acc[w*4+0]=lo[0]; acc[w*4+1]=lo[1]; acc[w*4+2]=hi[0]; acc[w*4+3]=hi[1];
    }
  }
  const unsigned short* myrow = col + (size_t)node*CAP;
  int c_ = cnt[node];
  int last = c_ - 1;
  for(int i=0; i<c_; i += U){
    int s[U];
    #pragma unroll
    for(int u=0;u<U;++u){
      int ii = i + u; ii = (ii < last) ? ii : last;
      s[u] = myrow[ii];
    }
    uint4 v[U];
    #pragma unroll
    for(int u=0;u<U;++u) v[u] = *(const uint4*)(yb + (size_t)s[u]*DB);
    #pragma unroll
    for(int u=0;u<U;++u){
      if(i + u < c_){
        const unsigned* qw = (const unsigned*)&v[u];
        #pragma unroll
        for(int w=0;w<4;++w){
          f2 lo = __builtin_amdgcn_cvt_pk_f32_fp8(qw[w], false);
          f2 hi = __builtin_amdgcn_cvt_pk_f32_fp8(qw[w], true);
          acc[w*4+0]+=lo[0]; acc[w*4+1]+=lo[1]; acc[w*4+2]+=hi[0]; acc[w*4+3]+=hi[1];
        }
      }
    }
  }
  float dv = dinv[node];
  us8 w0, w1;
  #pragma unroll
  for(int j=0;j<8;++j){ w0[j]=f2bf(acc[j]*dv); w1[j]=f2bf(acc[8+j]*dv); }
  int c = gl*16;
  *(us8*)(out0 + (size_t)node*DB + c)     = w0;
  *(us8*)(out0 + (size_t)node*DB + c + 8) = w1;
}

// ---------------- unified GEMM: B in LDS (XOR-swizzled, unpadded), A direct.
// 512 threads (8 waves), tile = 128 rows, wave = 16 rows x 128 cols.
// KB = K elems (256 or 128). MODE: 0=Zb z-half, 1=Zb h-half, 2=r->yq, 3=final.
template<int KB, int MODE>
__global__ __launch_bounds__(512) void k_gemm(
    const unsigned short* __restrict__ A, int astride,
    const unsigned short* __restrict__ Bsrc,   // row j at Bsrc + j*256 (+built-in col offset)
    const unsigned short* __restrict__ Zr, unsigned short* __restrict__ Zw,
    const float* __restrict__ hl, const float* __restrict__ dinv,
    const float* __restrict__ b1, const float* __restrict__ b2,
    const float* __restrict__ b3, const float* __restrict__ b4,
    unsigned char* __restrict__ yq, float* __restrict__ outp,
    unsigned char* __restrict__ y2out, int nrows)
{
  __shared__ unsigned char Bs[KB*256];   // 128 cols x KB*2 bytes
  const int t = threadIdx.x;
  constexpr int CPR = KB/8;              // 16B chunks per row
  for(int c = t; c < 128*CPR; c += 512){
    int j = c / CPR, kc = c % CPR;
    us8 v = *(const us8*)(Bsrc + (size_t)j*256 + kc*8);
    *(us8*)(Bs + ((j*(KB*2) + kc*16) ^ ((j&7)<<4))) = v;
  }
  __syncthreads();
  const int lane = t & 63, lo = lane & 15, hi = lane >> 4;
  const int r0 = blockIdx.x*128 + (t>>6)*16;
  const int arow = r0 + lo;
  const unsigned short* Ap = A + (size_t)(arow < nrows ? arow : 0)*astride + hi*8;
  f4 acc[8];
  #pragma unroll
  for(int n=0;n<8;++n) acc[n]=(f4)0.f;
  #pragma unroll
  for(int kk=0;kk<KB/32;++kk){
    s8 a = (arow<nrows) ? *(const s8*)(Ap + kk*32) : (s8)(short)0;
    #pragma unroll
    for(int n=0;n<8;++n){
      int j = n*16+lo;
      s8 b = *(const s8*)(Bs + ((j*(KB*2) + kk*64 + hi*16) ^ ((lo&7)<<4)));
      acc[n] = __builtin_amdgcn_mfma_f32_16x16x32_bf16(a, b, acc[n], 0,0,0);
    }
  }
  #pragma unroll
  for(int n=0;n<8;++n){
    const int colv = n*16 + lo;
    float bz = 0.f, bhv = 0.f;
    if constexpr(MODE==2){ bz = b1[colv] + b2[colv]; }
    if constexpr(MODE==3){ bz = b1[colv] + b2[colv]; bhv = b3[colv] + b4[colv]; }
    #pragma unroll
    for(int tt=0;tt<4;++tt){
      int row = r0 + hi*4 + tt;
      if(row >= nrows) continue;
      float v = acc[n][tt];
      if constexpr(MODE==0){
        Zw[(size_t)row*256 + colv] = f2bf(v);
      } else if constexpr(MODE==1){
        Zw[(size_t)row*256 + 128 + colv] = f2bf(v);
      } else if constexpr(MODE==2){
        float r = sigm(v + bz);
        float q = dinv[row] * r * hl[(size_t)row*128 + colv];
        unsigned pk = __builtin_amdgcn_cvt_pk_fp8_f32(q, q, 0, false);
        yq[(size_t)row*128 + colv] = (unsigned char)(pk & 0xff);
      } else {
        float z  = sigm(bf2f(Zr[(size_t)row*256 + colv]) + bz);
        float ht = tanhf(v + bf2f(Zr[(size_t)row*256 + 128 + colv]) + bhv);
        float ov = z*hl[(size_t)row*128 + colv] + (1.f - z)*ht;
        outp[(size_t)row*128 + colv] = ov;
        if(y2out){
          float q = dinv[row] * ov;
          unsigned pk = __builtin_amdgcn_cvt_pk_fp8_f32(q, q, 0, false);
          y2out[(size_t)row*256 + colv] = (unsigned char)(pk & 0xff);
        }
      }
    }
  }
}

extern "C" void kernel_launch(void* const* d_in, const int* in_sizes, int n_in,
                              void* d_out, int out_size, void* d_ws, size_t ws_size,
                              hipStream_t stream){
  const float* x  = (const float*)d_in[0];
  const int*   ei = (const int*)d_in[1];
  const float* h  = (const float*)d_in[2];
  const float* Wx = (const float*)d_in[3];
  const float* bx = (const float*)d_in[4];
  const float* Wh = (const float*)d_in[5];
  const float* bh = (const float*)d_in[6];
  float* out = (float*)d_out;

  const int N = in_sizes[0] / 128;
  const int E = in_sizes[1] / 2;
  const int L = in_sizes[2] / in_sizes[0];
  const int* src = ei;
  const int* dst = ei + E;

  char* w = (char*)d_ws;
  auto alloc = [&](size_t b)->char*{ char* p = w; w += (b + 255) & ~(size_t)255; return p; };
  int* cnt = (int*)alloc((size_t)N*sizeof(int));
  unsigned short* col = (unsigned short*)alloc((size_t)N*CAP*sizeof(short));
  float* dinv = (float*)alloc((size_t)N*sizeof(float));
  unsigned short* WT = (unsigned short*)alloc((size_t)6*32768*sizeof(short));
  unsigned char* y2 = (unsigned char*)alloc((size_t)N*256);
  unsigned short* axah = (unsigned short*)alloc((size_t)N*256*sizeof(short));
  unsigned char* yq = (unsigned char*)alloc((size_t)N*128);
  unsigned short* aq = (unsigned short*)alloc((size_t)N*128*sizeof(short));
  unsigned short* Zb = (unsigned short*)alloc((size_t)N*256*sizeof(short));
  unsigned* ebuf = (unsigned*)alloc((size_t)NRG*NBB*SEGC*sizeof(unsigned));
  int* cnt2 = (int*)alloc((size_t)NRG*NBB*sizeof(int));

  const int gN = (N + 255)/256;
  const int gew = (N*32 + 255)/256;
  const int g128 = (N + 127)/128;
  const int gagg4 = (N + 15)/16;
  const int gagg2 = (N + 31)/32;

  k_bucket<<<NBB,256,0,stream>>>(src, dst, ebuf, cnt2, E, N);
  k_build2<<<NRG,256,0,stream>>>(ebuf, cnt2, cnt, col, N);
  k_setup<<<gN + 768,256,0,stream>>>(cnt, dinv, N, Wx, Wh, WT);

  for(int l=0; l<L; ++l){
    const float* inp = (l==0) ? x : (out + (size_t)(l-1)*N*128);
    const float* hl  = h + (size_t)l*N*128;
    const float* bxz = bx + (size_t)(l*3+0)*128; const float* bhz = bh + (size_t)(l*3+0)*128;
    const float* bxr = bx + (size_t)(l*3+1)*128; const float* bhr = bh + (size_t)(l*3+1)*128;
    const float* bxh = bx + (size_t)(l*3+2)*128; const float* bhh = bh + (size_t)(l*3+2)*128;
    const unsigned short* Wz = WT + (size_t)(l*3+0)*32768;  // [Wxz;Whz]
    const unsigned short* Wr = WT + (size_t)(l*3+1)*32768;  // [Wxr;Whr]
    const unsigned short* Wh2= WT + (size_t)(l*3+2)*32768;  // [Wxh;Whh]

    if(l==0) k_scale2<1><<<gew,256,0,stream>>>(inp, hl, dinv, y2, N);
    else     k_scale2<0><<<gew,256,0,stream>>>(inp, hl, dinv, y2, N);
    k_agg<256><<<gagg4,256,0,stream>>>(y2, cnt, col, dinv, axah, N);
    // z-pre: Zb[:,0:128] = bf16(axah @ [Wxz;Whz]), K=256
    k_gemm<256,0><<<g128,512,0,stream>>>(axah, 256, Wz, nullptr, Zb,
        nullptr, nullptr, nullptr, nullptr, nullptr, nullptr, nullptr, nullptr, nullptr, N);
    // ht-part: Zb[:,128:256] = bf16(axah[:,0:128] @ Wxh), K=128
    k_gemm<128,1><<<g128,512,0,stream>>>(axah, 256, Wh2, nullptr, Zb,
        nullptr, nullptr, nullptr, nullptr, nullptr, nullptr, nullptr, nullptr, nullptr, N);
    // r: yq = fp8(dinv*sigm(axah@[Wxr;Whr] + b)*hl), K=256
    k_gemm<256,2><<<g128,512,0,stream>>>(axah, 256, Wr, nullptr, nullptr,
        hl, dinv, bxr, bhr, nullptr, nullptr, yq, nullptr, nullptr, N);
    k_agg<128><<<gagg2,256,0,stream>>>(yq, cnt, col, dinv, aq, N);
    // final: K=128, B = Whh = cols 128.. of Wh2
    k_gemm<128,3><<<g128,512,0,stream>>>(aq, 128, Wh2 + 128, Zb, nullptr,
        hl, dinv, bxz, bhz, bxh, bhh, nullptr, out + (size_t)l*N*128,
        (l+1<L) ? y2 : nullptr, N);
  }
}

// Round 14
// 382.066 us; speedup vs baseline: 1.4061x; 1.0674x over previous
//
#include <hip/hip_runtime.h>

typedef __attribute__((ext_vector_type(8))) unsigned short us8;
typedef __attribute__((ext_vector_type(8))) short s8;
typedef __attribute__((ext_vector_type(4))) float f4;
typedef __attribute__((ext_vector_type(2))) float f2;

#define DEV static __device__ __forceinline__
#define CAP 128
#define NRG 128
#define NBB 256
#define SEGC 128

DEV float bf2f(unsigned short h){ return __uint_as_float(((unsigned)h)<<16); }
DEV unsigned short f2bf(float f){
  unsigned x = __float_as_uint(f);
  x += 0x7fffu + ((x>>16)&1u);
  return (unsigned short)(x>>16);
}
DEV float sigm(float x){ return 1.f/(1.f + __expf(-x)); }

// ---------------- setup kernels ----------------
__global__ __launch_bounds__(256) void k_bucket(const int* __restrict__ src,
    const int* __restrict__ dst, unsigned* __restrict__ buf,
    int* __restrict__ cnt2, int e, int n){
  __shared__ int lcnt[NRG];
  int b = blockIdx.x;
  for(int i=threadIdx.x;i<NRG;i+=256) lcnt[i] = 0;
  __syncthreads();
  int chunk = (e + NBB - 1)/NBB;
  int lo = b*chunk;
  int hi = lo + chunk; if(hi>e) hi=e;
  for(int i = lo + threadIdx.x; i < hi; i += 256){
    int d = dst[i], s = src[i];
    int r = (d*NRG)/n;
    int pos = atomicAdd(&lcnt[r], 1);
    if(pos < SEGC)
      buf[((size_t)r*NBB + b)*SEGC + pos] = ((unsigned)d<<16) | (unsigned)s;
  }
  __syncthreads();
  for(int i=threadIdx.x;i<NRG;i+=256) cnt2[i*NBB + b] = lcnt[i];
}

__global__ __launch_bounds__(256) void k_build2(const unsigned* __restrict__ buf,
    const int* __restrict__ cnt2, int* __restrict__ cnt,
    unsigned short* __restrict__ col, int n){
  int r = blockIdx.x;
  int lo = (r*n + NRG-1)/NRG;
  int hi = ((r+1)*n + NRG-1)/NRG;
  int span = hi - lo;
  __shared__ int lc[512];
  for(int i=threadIdx.x; i<span; i+=256) lc[i] = 0;
  __syncthreads();
  int lane = threadIdx.x & 63;
  for(int seg = threadIdx.x>>6; seg < NBB; seg += 4){
    int c = cnt2[r*NBB + seg]; if(c > SEGC) c = SEGC;
    const unsigned* p = buf + ((size_t)r*NBB + seg)*SEGC;
    for(int i = lane; i < c; i += 64){
      unsigned v = p[i];
      int d = (int)(v >> 16), s = (int)(v & 0xffffu);
      int slot = atomicAdd(&lc[d - lo], 1);
      col[(size_t)d*CAP + slot] = (unsigned short)s;
    }
  }
  __syncthreads();
  for(int i=threadIdx.x; i<span; i+=256) cnt[lo + i] = lc[i];
}

// dinv + concatenated weight prep: WT[m][j][k] (m = l*3+g, j out-col, k 0..255)
__global__ void k_setup(const int* __restrict__ cnt, float* __restrict__ dinv, int n,
                        const float* __restrict__ Wx, const float* __restrict__ Wh,
                        unsigned short* __restrict__ WT){
  int gN = (n + 255)/256;
  int b = blockIdx.x;
  if(b < gN){
    int i = b*256 + threadIdx.x;
    if(i<n) dinv[i] = rsqrtf((float)cnt[i] + 1.0f);
  } else {
    int i = (b-gN)*256 + threadIdx.x;   // < 6*32768
    int m = i >> 15;
    int rem = i & 32767;
    int j = rem >> 8;
    int k = rem & 255;
    float v = (k<128) ? Wx[((size_t)m*128 + k)*128 + j]
                      : Wh[((size_t)m*128 + (k-128))*128 + j];
    WT[(size_t)m*32768 + j*256 + k] = f2bf(v);
  }
}

// ---------------- per-layer kernels ----------------
// layer-0 only: y2 = fp8(dinv*[x | h0])
__global__ void k_scale2(const float* __restrict__ inp, const float* __restrict__ hl,
                         const float* __restrict__ dinv, unsigned char* __restrict__ y2, int n){
  int i = blockIdx.x*blockDim.x+threadIdx.x;
  if(i >= n*32) return;
  int node = i>>5, d0 = (i&31)*4;
  float dv = dinv[node];
  f4 a = *(const f4*)(inp + (size_t)node*128 + d0);
  f4 b = *(const f4*)(hl  + (size_t)node*128 + d0);
  unsigned pa = __builtin_amdgcn_cvt_pk_fp8_f32(dv*a[0], dv*a[1], 0, false);
  pa = __builtin_amdgcn_cvt_pk_fp8_f32(dv*a[2], dv*a[3], pa, true);
  unsigned pb = __builtin_amdgcn_cvt_pk_fp8_f32(dv*b[0], dv*b[1], 0, false);
  pb = __builtin_amdgcn_cvt_pk_fp8_f32(dv*b[2], dv*b[3], pb, true);
  *(unsigned*)(y2 + (size_t)node*256 + d0)       = pa;
  *(unsigned*)(y2 + (size_t)node*256 + 128 + d0) = pb;
}

// CSR aggregation over fp8 rows; output bf16 [n][DB]
template<int DB>
__global__ __launch_bounds__(256) void k_agg(const unsigned char* __restrict__ y,
    const int* __restrict__ cnt, const unsigned short* __restrict__ col,
    const float* __restrict__ dinv, unsigned short* __restrict__ out0, int n)
{
  constexpr int GL = DB/16;
  constexpr int NG = 64/GL;
  constexpr int U = 8;
  int tid = threadIdx.x;
  int wave = tid>>6, lane = tid&63;
  int g = lane/GL, gl = lane%GL;
  int node = blockIdx.x*(4*NG) + wave*NG + g;
  if(node >= n) return;
  const unsigned char* yb = y + (size_t)gl*16;
  float acc[16];
  {
    uint4 q = *(const uint4*)(yb + (size_t)node*DB);
    const unsigned* qw = (const unsigned*)&q;
    #pragma unroll
    for(int w=0;w<4;++w){
      f2 lo = __builtin_amdgcn_cvt_pk_f32_fp8(qw[w], false);
      f2 hi = __builtin_amdgcn_cvt_pk_f32_fp8(qw[w], true);
      acc[w*4+0]=lo[0]; acc[w*4+1]=lo[1]; acc[w*4+2]=hi[0]; acc[w*4+3]=hi[1];
    }
  }
  const unsigned short* myrow = col + (size_t)node*CAP;
  int c_ = cnt[node];
  int last = c_ - 1;
  for(int i=0; i<c_; i += U){
    int s[U];
    #pragma unroll
    for(int u=0;u<U;++u){
      int ii = i + u; ii = (ii < last) ? ii : last;
      s[u] = myrow[ii];
    }
    uint4 v[U];
    #pragma unroll
    for(int u=0;u<U;++u) v[u] = *(const uint4*)(yb + (size_t)s[u]*DB);
    #pragma unroll
    for(int u=0;u<U;++u){
      if(i + u < c_){
        const unsigned* qw = (const unsigned*)&v[u];
        #pragma unroll
        for(int w=0;w<4;++w){
          f2 lo = __builtin_amdgcn_cvt_pk_f32_fp8(qw[w], false);
          f2 hi = __builtin_amdgcn_cvt_pk_f32_fp8(qw[w], true);
          acc[w*4+0]+=lo[0]; acc[w*4+1]+=lo[1]; acc[w*4+2]+=hi[0]; acc[w*4+3]+=hi[1];
        }
      }
    }
  }
  float dv = dinv[node];
  us8 w0, w1;
  #pragma unroll
  for(int j=0;j<8;++j){ w0[j]=f2bf(acc[j]*dv); w1[j]=f2bf(acc[8+j]*dv); }
  int c = gl*16;
  *(us8*)(out0 + (size_t)node*DB + c)     = w0;
  *(us8*)(out0 + (size_t)node*DB + c + 8) = w1;
}

// ---- LDS B-staging helpers (XOR-swizzled, unpadded) ----
// KB = K elems; row j occupies KB*2 bytes.
template<int KB>
DEV void stageB512(unsigned char* Bs, const unsigned short* Bsrc, int srcStride,
                   int srcOff, int t){
  constexpr int CPR = KB/8;
  #pragma unroll
  for(int i=0;i<128*CPR/512;++i){
    int c = t + i*512;
    int j = c / CPR, kc = c % CPR;
    us8 v = *(const us8*)(Bsrc + (size_t)j*srcStride + srcOff + kc*8);
    *(us8*)(Bs + ((j*(KB*2) + kc*16) ^ ((j&7)<<4))) = v;
  }
}
template<int KB>
DEV void mfmaK(const unsigned char* Bs, const unsigned short* A, int astride,
               int arow, int nrows, int lo, int hi, f4 (&acc)[8]){
  const unsigned short* Ap = A + (size_t)(arow < nrows ? arow : 0)*astride + hi*8;
  #pragma unroll
  for(int kk=0;kk<KB/32;++kk){
    s8 a = (arow<nrows) ? *(const s8*)(Ap + kk*32) : (s8)(short)0;
    #pragma unroll
    for(int n=0;n<8;++n){
      int j = n*16+lo;
      s8 b = *(const s8*)(Bs + ((j*(KB*2) + kk*64 + hi*16) ^ ((lo&7)<<4)));
      acc[n] = __builtin_amdgcn_mfma_f32_16x16x32_bf16(a, b, acc[n], 0,0,0);
    }
  }
}

// RH: stage1 yq = fp8(dinv*sigm(axah@[Wxr;Whr]+b)*hl)  [K=256]
//     stage2 Zbh = bf16(axah_x @ Wxh)                  [K=128]
__global__ __launch_bounds__(512) void k_gemmRH(
    const unsigned short* __restrict__ axah, const unsigned short* __restrict__ Wr,
    const unsigned short* __restrict__ Wh2, const float* __restrict__ hl,
    const float* __restrict__ dinv, const float* __restrict__ bxr,
    const float* __restrict__ bhr, unsigned char* __restrict__ yq,
    unsigned short* __restrict__ Zbh, int nrows)
{
  __shared__ unsigned char Bs[65536];
  const int t = threadIdx.x, lane = t & 63, lo = lane & 15, hi = lane >> 4;
  const int r0 = blockIdx.x*128 + (t>>6)*16;
  const int arow = r0 + lo;
  f4 acc[8];
  #pragma unroll
  for(int n=0;n<8;++n) acc[n]=(f4)0.f;
  stageB512<256>(Bs, Wr, 256, 0, t);
  __syncthreads();
  mfmaK<256>(Bs, axah, 256, arow, nrows, lo, hi, acc);
  #pragma unroll
  for(int n=0;n<8;++n){
    const int colv = n*16 + lo;
    float bz = bxr[colv] + bhr[colv];
    #pragma unroll
    for(int tt=0;tt<4;++tt){
      int row = r0 + hi*4 + tt;
      if(row < nrows){
        float r = sigm(acc[n][tt] + bz);
        float q = dinv[row] * r * hl[(size_t)row*128 + colv];
        unsigned pk = __builtin_amdgcn_cvt_pk_fp8_f32(q, q, 0, false);
        yq[(size_t)row*128 + colv] = (unsigned char)(pk & 0xff);
      }
    }
  }
  __syncthreads();
  stageB512<128>(Bs, Wh2, 256, 0, t);   // Wxh = k 0..127 of Wh2 rows
  __syncthreads();
  #pragma unroll
  for(int n=0;n<8;++n) acc[n]=(f4)0.f;
  mfmaK<128>(Bs, axah, 256, arow, nrows, lo, hi, acc);
  #pragma unroll
  for(int n=0;n<8;++n){
    const int colv = n*16 + lo;
    #pragma unroll
    for(int tt=0;tt<4;++tt){
      int row = r0 + hi*4 + tt;
      if(row < nrows) Zbh[(size_t)row*128 + colv] = f2bf(acc[n][tt]);
    }
  }
}

// ZF: stage1 accZ = axah@[Wxz;Whz] (K=256, in regs)
//     stage2 accH = aq@Whh (K=128)
//     out = sigm(accZ+bz)*hl + (1-sigm)*tanh(accH + Zbh + bh)
//     y2out (if next layer): x-half=fp8(dinv*out), h-half=fp8(dinv*hnext)
__global__ __launch_bounds__(512) void k_gemmZF(
    const unsigned short* __restrict__ axah, const unsigned short* __restrict__ aq,
    const unsigned short* __restrict__ Wz, const unsigned short* __restrict__ Wh2,
    const unsigned short* __restrict__ Zbh, const float* __restrict__ hl,
    const float* __restrict__ hnext, const float* __restrict__ dinv,
    const float* __restrict__ bxz, const float* __restrict__ bhz,
    const float* __restrict__ bxh, const float* __restrict__ bhh,
    float* __restrict__ outp, unsigned char* __restrict__ y2out, int nrows)
{
  __shared__ unsigned char Bs[65536];
  const int t = threadIdx.x, lane = t & 63, lo = lane & 15, hi = lane >> 4;
  const int r0 = blockIdx.x*128 + (t>>6)*16;
  const int arow = r0 + lo;
  f4 accZ[8], accH[8];
  #pragma unroll
  for(int n=0;n<8;++n){ accZ[n]=(f4)0.f; accH[n]=(f4)0.f; }
  stageB512<256>(Bs, Wz, 256, 0, t);
  __syncthreads();
  mfmaK<256>(Bs, axah, 256, arow, nrows, lo, hi, accZ);
  __syncthreads();
  stageB512<128>(Bs, Wh2, 256, 128, t);   // Whh = k 128..255 of Wh2 rows
  __syncthreads();
  mfmaK<128>(Bs, aq, 128, arow, nrows, lo, hi, accH);
  #pragma unroll
  for(int n=0;n<8;++n){
    const int colv = n*16 + lo;
    float bz = bxz[colv] + bhz[colv];
    float bh = bxh[colv] + bhh[colv];
    #pragma unroll
    for(int tt=0;tt<4;++tt){
      int row = r0 + hi*4 + tt;
      if(row >= nrows) continue;
      float z  = sigm(accZ[n][tt] + bz);
      float ht = tanhf(accH[n][tt] + bf2f(Zbh[(size_t)row*128 + colv]) + bh);
      float ov = z*hl[(size_t)row*128 + colv] + (1.f - z)*ht;
      outp[(size_t)row*128 + colv] = ov;
      if(y2out){
        float dv = dinv[row];
        unsigned pk = __builtin_amdgcn_cvt_pk_fp8_f32(dv*ov, dv*ov, 0, false);
        y2out[(size_t)row*256 + colv] = (unsigned char)(pk & 0xff);
        float hv = dv * hnext[(size_t)row*128 + colv];
        unsigned ph = __builtin_amdgcn_cvt_pk_fp8_f32(hv, hv, 0, false);
        y2out[(size_t)row*256 + 128 + colv] = (unsigned char)(ph & 0xff);
      }
    }
  }
}

extern "C" void kernel_launch(void* const* d_in, const int* in_sizes, int n_in,
                              void* d_out, int out_size, void* d_ws, size_t ws_size,
                              hipStream_t stream){
  const float* x  = (const float*)d_in[0];
  const int*   ei = (const int*)d_in[1];
  const float* h  = (const float*)d_in[2];
  const float* Wx = (const float*)d_in[3];
  const float* bx = (const float*)d_in[4];
  const float* Wh = (const float*)d_in[5];
  const float* bh = (const float*)d_in[6];
  float* out = (float*)d_out;

  const int N = in_sizes[0] / 128;
  const int E = in_sizes[1] / 2;
  const int L = in_sizes[2] / in_sizes[0];
  const int* src = ei;
  const int* dst = ei + E;

  char* w = (char*)d_ws;
  auto alloc = [&](size_t b)->char*{ char* p = w; w += (b + 255) & ~(size_t)255; return p; };
  int* cnt = (int*)alloc((size_t)N*sizeof(int));
  unsigned short* col = (unsigned short*)alloc((size_t)N*CAP*sizeof(short));
  float* dinv = (float*)alloc((size_t)N*sizeof(float));
  unsigned short* WT = (unsigned short*)alloc((size_t)6*32768*sizeof(short));
  unsigned char* y2 = (unsigned char*)alloc((size_t)N*256);
  unsigned short* axah = (unsigned short*)alloc((size_t)N*256*sizeof(short));
  unsigned char* yq = (unsigned char*)alloc((size_t)N*128);
  unsigned short* aq = (unsigned short*)alloc((size_t)N*128*sizeof(short));
  unsigned short* Zbh = (unsigned short*)alloc((size_t)N*128*sizeof(short));
  unsigned* ebuf = (unsigned*)alloc((size_t)NRG*NBB*SEGC*sizeof(unsigned));
  int* cnt2 = (int*)alloc((size_t)NRG*NBB*sizeof(int));

  const int gN = (N + 255)/256;
  const int gew = (N*32 + 255)/256;
  const int g128 = (N + 127)/128;
  const int gagg4 = (N + 15)/16;
  const int gagg2 = (N + 31)/32;

  k_bucket<<<NBB,256,0,stream>>>(src, dst, ebuf, cnt2, E, N);
  k_build2<<<NRG,256,0,stream>>>(ebuf, cnt2, cnt, col, N);
  k_setup<<<gN + 768,256,0,stream>>>(cnt, dinv, N, Wx, Wh, WT);

  for(int l=0; l<L; ++l){
    const float* hl  = h + (size_t)l*N*128;
    const float* bxz = bx + (size_t)(l*3+0)*128; const float* bhz = bh + (size_t)(l*3+0)*128;
    const float* bxr = bx + (size_t)(l*3+1)*128; const float* bhr = bh + (size_t)(l*3+1)*128;
    const float* bxh = bx + (size_t)(l*3+2)*128; const float* bhh = bh + (size_t)(l*3+2)*128;
    const unsigned short* Wz = WT + (size_t)(l*3+0)*32768;
    const unsigned short* Wr = WT + (size_t)(l*3+1)*32768;
    const unsigned short* Wh2= WT + (size_t)(l*3+2)*32768;

    if(l==0) k_scale2<<<gew,256,0,stream>>>(x, hl, dinv, y2, N);
    k_agg<256><<<gagg4,256,0,stream>>>(y2, cnt, col, dinv, axah, N);
    k_gemmRH<<<g128,512,0,stream>>>(axah, Wr, Wh2, hl, dinv, bxr, bhr, yq, Zbh, N);
    k_agg<128><<<gagg2,256,0,stream>>>(yq, cnt, col, dinv, aq, N);
    k_gemmZF<<<g128,512,0,stream>>>(axah, aq, Wz, Wh2, Zbh, hl,
        (l+1<L) ? (h + (size_t)(l+1)*N*128) : nullptr, dinv,
        bxz, bhz, bxh, bhh, out + (size_t)l*N*128,
        (l+1<L) ? y2 : nullptr, N);
  }
}

// Round 16
// 370.639 us; speedup vs baseline: 1.4495x; 1.0308x over previous
//
#include <hip/hip_runtime.h>

typedef __attribute__((ext_vector_type(8))) unsigned short us8;
typedef __attribute__((ext_vector_type(8))) short s8;
typedef __attribute__((ext_vector_type(4))) float f4;
typedef __attribute__((ext_vector_type(2))) float f2;

#define DEV static __device__ __forceinline__
#define CAP 128
#define NRG 128
#define NBB 256
#define SEGC 128

DEV float bf2f(unsigned short h){ return __uint_as_float(((unsigned)h)<<16); }
DEV unsigned short f2bf(float f){
  unsigned x = __float_as_uint(f);
  x += 0x7fffu + ((x>>16)&1u);
  return (unsigned short)(x>>16);
}
DEV float sigm(float x){ return 1.f/(1.f + __expf(-x)); }

// ---------------- setup kernels ----------------
__global__ __launch_bounds__(256) void k_bucket(const int* __restrict__ src,
    const int* __restrict__ dst, unsigned* __restrict__ buf,
    int* __restrict__ cnt2, int e, int n){
  __shared__ int lcnt[NRG];
  int b = blockIdx.x;
  for(int i=threadIdx.x;i<NRG;i+=256) lcnt[i] = 0;
  __syncthreads();
  int chunk = (e + NBB - 1)/NBB;
  int lo = b*chunk;
  int hi = lo + chunk; if(hi>e) hi=e;
  for(int i = lo + threadIdx.x; i < hi; i += 256){
    int d = dst[i], s = src[i];
    int r = (d*NRG)/n;
    int pos = atomicAdd(&lcnt[r], 1);
    if(pos < SEGC)
      buf[((size_t)r*NBB + b)*SEGC + pos] = ((unsigned)d<<16) | (unsigned)s;
  }
  __syncthreads();
  for(int i=threadIdx.x;i<NRG;i+=256) cnt2[i*NBB + b] = lcnt[i];
}

__global__ __launch_bounds__(256) void k_build2(const unsigned* __restrict__ buf,
    const int* __restrict__ cnt2, int* __restrict__ cnt,
    unsigned short* __restrict__ col, int n){
  int r = blockIdx.x;
  int lo = (r*n + NRG-1)/NRG;
  int hi = ((r+1)*n + NRG-1)/NRG;
  int span = hi - lo;
  __shared__ int lc[512];
  for(int i=threadIdx.x; i<span; i+=256) lc[i] = 0;
  __syncthreads();
  int lane = threadIdx.x & 63;
  for(int seg = threadIdx.x>>6; seg < NBB; seg += 4){
    int c = cnt2[r*NBB + seg]; if(c > SEGC) c = SEGC;
    const unsigned* p = buf + ((size_t)r*NBB + seg)*SEGC;
    for(int i = lane; i < c; i += 64){
      unsigned v = p[i];
      int d = (int)(v >> 16), s = (int)(v & 0xffffu);
      int slot = atomicAdd(&lc[d - lo], 1);
      col[(size_t)d*CAP + slot] = (unsigned short)s;
    }
  }
  __syncthreads();
  for(int i=threadIdx.x; i<span; i+=256) cnt[lo + i] = lc[i];
}

// dinv + concatenated weight prep: WT[m][j][k] (m = l*3+g, j out-col, k 0..255)
__global__ void k_setup(const int* __restrict__ cnt, float* __restrict__ dinv, int n,
                        const float* __restrict__ Wx, const float* __restrict__ Wh,
                        unsigned short* __restrict__ WT){
  int gN = (n + 255)/256;
  int b = blockIdx.x;
  if(b < gN){
    int i = b*256 + threadIdx.x;
    if(i<n) dinv[i] = rsqrtf((float)cnt[i] + 1.0f);
  } else {
    int i = (b-gN)*256 + threadIdx.x;   // < 6*32768
    int m = i >> 15;
    int rem = i & 32767;
    int j = rem >> 8;
    int k = rem & 255;
    float v = (k<128) ? Wx[((size_t)m*128 + k)*128 + j]
                      : Wh[((size_t)m*128 + (k-128))*128 + j];
    WT[(size_t)m*32768 + j*256 + k] = f2bf(v);
  }
}

// ---------------- per-layer kernels ----------------
// layer-0 only: y2 = fp8(dinv*[x | h0])
__global__ void k_scale2(const float* __restrict__ inp, const float* __restrict__ hl,
                         const float* __restrict__ dinv, unsigned char* __restrict__ y2, int n){
  int i = blockIdx.x*blockDim.x+threadIdx.x;
  if(i >= n*32) return;
  int node = i>>5, d0 = (i&31)*4;
  float dv = dinv[node];
  f4 a = *(const f4*)(inp + (size_t)node*128 + d0);
  f4 b = *(const f4*)(hl  + (size_t)node*128 + d0);
  unsigned pa = __builtin_amdgcn_cvt_pk_fp8_f32(dv*a[0], dv*a[1], 0, false);
  pa = __builtin_amdgcn_cvt_pk_fp8_f32(dv*a[2], dv*a[3], pa, true);
  unsigned pb = __builtin_amdgcn_cvt_pk_fp8_f32(dv*b[0], dv*b[1], 0, false);
  pb = __builtin_amdgcn_cvt_pk_fp8_f32(dv*b[2], dv*b[3], pb, true);
  *(unsigned*)(y2 + (size_t)node*256 + d0)       = pa;
  *(unsigned*)(y2 + (size_t)node*256 + 128 + d0) = pb;
}

// CSR aggregation over fp8 rows; output bf16 [n][DB]
template<int DB>
__global__ __launch_bounds__(256) void k_agg(const unsigned char* __restrict__ y,
    const int* __restrict__ cnt, const unsigned short* __restrict__ col,
    const float* __restrict__ dinv, unsigned short* __restrict__ out0, int n)
{
  constexpr int GL = DB/16;
  constexpr int NG = 64/GL;
  constexpr int U = 8;
  int tid = threadIdx.x;
  int wave = tid>>6, lane = tid&63;
  int g = lane/GL, gl = lane%GL;
  int node = blockIdx.x*(4*NG) + wave*NG + g;
  if(node >= n) return;
  const unsigned char* yb = y + (size_t)gl*16;
  float acc[16];
  {
    uint4 q = *(const uint4*)(yb + (size_t)node*DB);
    const unsigned* qw = (const unsigned*)&q;
    #pragma unroll
    for(int w=0;w<4;++w){
      f2 lo = __builtin_amdgcn_cvt_pk_f32_fp8(qw[w], false);
      f2 hi = __builtin_amdgcn_cvt_pk_f32_fp8(qw[w], true);
      acc[w*4+0]=lo[0]; acc[w*4+1]=lo[1]; acc[w*4+2]=hi[0]; acc[w*4+3]=hi[1];
    }
  }
  const unsigned short* myrow = col + (size_t)node*CAP;
  int c_ = cnt[node];
  int last = c_ - 1;
  for(int i=0; i<c_; i += U){
    int s[U];
    #pragma unroll
    for(int u=0;u<U;++u){
      int ii = i + u; ii = (ii < last) ? ii : last;
      s[u] = myrow[ii];
    }
    uint4 v[U];
    #pragma unroll
    for(int u=0;u<U;++u) v[u] = *(const uint4*)(yb + (size_t)s[u]*DB);
    #pragma unroll
    for(int u=0;u<U;++u){
      if(i + u < c_){
        const unsigned* qw = (const unsigned*)&v[u];
        #pragma unroll
        for(int w=0;w<4;++w){
          f2 lo = __builtin_amdgcn_cvt_pk_f32_fp8(qw[w], false);
          f2 hi = __builtin_amdgcn_cvt_pk_f32_fp8(qw[w], true);
          acc[w*4+0]+=lo[0]; acc[w*4+1]+=lo[1]; acc[w*4+2]+=hi[0]; acc[w*4+3]+=hi[1];
        }
      }
    }
  }
  float dv = dinv[node];
  us8 w0, w1;
  #pragma unroll
  for(int j=0;j<8;++j){ w0[j]=f2bf(acc[j]*dv); w1[j]=f2bf(acc[8+j]*dv); }
  int c = gl*16;
  *(us8*)(out0 + (size_t)node*DB + c)     = w0;
  *(us8*)(out0 + (size_t)node*DB + c + 8) = w1;
}

// ---- LDS B-staging helpers (XOR-swizzled, unpadded) ----
template<int KB>
DEV void stageB512(unsigned char* Bs, const unsigned short* Bsrc, int srcStride,
                   int srcOff, int t){
  constexpr int CPR = KB/8;
  #pragma unroll
  for(int i=0;i<128*CPR/512;++i){
    int c = t + i*512;
    int j = c / CPR, kc = c % CPR;
    us8 v = *(const us8*)(Bsrc + (size_t)j*srcStride + srcOff + kc*8);
    *(us8*)(Bs + ((j*(KB*2) + kc*16) ^ ((j&7)<<4))) = v;
  }
}
// prefetch NK A-fragments (16B each) into registers; zeroed if row OOB
template<int NK>
DEV void loadA(const unsigned short* A, int astride, int arow, int nrows, int hi,
               s8 (&a)[NK]){
  const unsigned short* Ap = A + (size_t)(arow < nrows ? arow : 0)*astride + hi*8;
  #pragma unroll
  for(int kk=0;kk<NK;++kk) a[kk] = *(const s8*)(Ap + kk*32);
  if(arow >= nrows){
    #pragma unroll
    for(int kk=0;kk<NK;++kk) a[kk] = (s8)(short)0;
  }
}
// MFMA from register A + LDS B; KB = LDS row elems, NK = K/32 steps, NA = |a|
template<int KB, int NK, int NA>
DEV void mfmaR(const unsigned char* Bs, const s8 (&a)[NA], int lo, int hi,
               f4 (&acc)[8]){
  static_assert(NK <= NA, "not enough A fragments");
  #pragma unroll
  for(int kk=0;kk<NK;++kk){
    #pragma unroll
    for(int n=0;n<8;++n){
      int j = n*16+lo;
      s8 b = *(const s8*)(Bs + ((j*(KB*2) + kk*64 + hi*16) ^ ((lo&7)<<4)));
      acc[n] = __builtin_amdgcn_mfma_f32_16x16x32_bf16(a[kk], b, acc[n], 0,0,0);
    }
  }
}

// RH: stage1 yq = fp8(dinv*sigm(axah@[Wxr;Whr]+b)*hl)  [K=256]
//     stage2 Zbh = bf16(axah_x @ Wxh)                  [K=128, A = a[0..3]]
__global__ __launch_bounds__(512) void k_gemmRH(
    const unsigned short* __restrict__ axah, const unsigned short* __restrict__ Wr,
    const unsigned short* __restrict__ Wh2, const float* __restrict__ hl,
    const float* __restrict__ dinv, const float* __restrict__ bxr,
    const float* __restrict__ bhr, unsigned char* __restrict__ yq,
    unsigned short* __restrict__ Zbh, int nrows)
{
  __shared__ unsigned char Bs[65536];
  const int t = threadIdx.x, lane = t & 63, lo = lane & 15, hi = lane >> 4;
  const int r0 = blockIdx.x*128 + (t>>6)*16;
  const int arow = r0 + lo;
  s8 a256[8];
  loadA<8>(axah, 256, arow, nrows, hi, a256);   // issued before staging
  stageB512<256>(Bs, Wr, 256, 0, t);
  f4 acc[8];
  #pragma unroll
  for(int n=0;n<8;++n) acc[n]=(f4)0.f;
  __syncthreads();
  mfmaR<256,8,8>(Bs, a256, lo, hi, acc);
  #pragma unroll
  for(int n=0;n<8;++n){
    const int colv = n*16 + lo;
    float bz = bxr[colv] + bhr[colv];
    #pragma unroll
    for(int tt=0;tt<4;++tt){
      int row = r0 + hi*4 + tt;
      if(row < nrows){
        float r = sigm(acc[n][tt] + bz);
        float q = dinv[row] * r * hl[(size_t)row*128 + colv];
        unsigned pk = __builtin_amdgcn_cvt_pk_fp8_f32(q, q, 0, false);
        yq[(size_t)row*128 + colv] = (unsigned char)(pk & 0xff);
      }
    }
  }
  __syncthreads();
  stageB512<128>(Bs, Wh2, 256, 0, t);   // Wxh = k 0..127 of Wh2 rows
  __syncthreads();
  #pragma unroll
  for(int n=0;n<8;++n) acc[n]=(f4)0.f;
  mfmaR<128,4,8>(Bs, a256, lo, hi, acc);  // uses a256[0..3] = x-half
  #pragma unroll
  for(int n=0;n<8;++n){
    const int colv = n*16 + lo;
    #pragma unroll
    for(int tt=0;tt<4;++tt){
      int row = r0 + hi*4 + tt;
      if(row < nrows) Zbh[(size_t)row*128 + colv] = f2bf(acc[n][tt]);
    }
  }
}

// ZF: accZ = axah@[Wxz;Whz] (K=256), accH = aq@Whh (K=128)
//     out = sigm(accZ+bz)*hl + (1-sigm)*tanh(accH + Zbh + bh)
//     y2out (if next layer): x-half=fp8(dinv*out), h-half=fp8(dinv*hnext)
__global__ __launch_bounds__(512) void k_gemmZF(
    const unsigned short* __restrict__ axah, const unsigned short* __restrict__ aq,
    const unsigned short* __restrict__ Wz, const unsigned short* __restrict__ Wh2,
    const unsigned short* __restrict__ Zbh, const float* __restrict__ hl,
    const float* __restrict__ hnext, const float* __restrict__ dinv,
    const float* __restrict__ bxz, const float* __restrict__ bhz,
    const float* __restrict__ bxh, const float* __restrict__ bhh,
    float* __restrict__ outp, unsigned char* __restrict__ y2out, int nrows)
{
  __shared__ unsigned char Bs[65536];
  const int t = threadIdx.x, lane = t & 63, lo = lane & 15, hi = lane >> 4;
  const int r0 = blockIdx.x*128 + (t>>6)*16;
  const int arow = r0 + lo;
  s8 a256[8], a128[4];
  loadA<8>(axah, 256, arow, nrows, hi, a256);   // all 12 A loads in flight
  loadA<4>(aq, 128, arow, nrows, hi, a128);
  stageB512<256>(Bs, Wz, 256, 0, t);
  f4 accZ[8], accH[8];
  #pragma unroll
  for(int n=0;n<8;++n){ accZ[n]=(f4)0.f; accH[n]=(f4)0.f; }
  __syncthreads();
  mfmaR<256,8,8>(Bs, a256, lo, hi, accZ);
  __syncthreads();
  stageB512<128>(Bs, Wh2, 256, 128, t);   // Whh = k 128..255 of Wh2 rows
  __syncthreads();
  mfmaR<128,4,4>(Bs, a128, lo, hi, accH);
  #pragma unroll
  for(int n=0;n<8;++n){
    const int colv = n*16 + lo;
    float bz = bxz[colv] + bhz[colv];
    float bh = bxh[colv] + bhh[colv];
    #pragma unroll
    for(int tt=0;tt<4;++tt){
      int row = r0 + hi*4 + tt;
      if(row >= nrows) continue;
      float z  = sigm(accZ[n][tt] + bz);
      float ht = tanhf(accH[n][tt] + bf2f(Zbh[(size_t)row*128 + colv]) + bh);
      float ov = z*hl[(size_t)row*128 + colv] + (1.f - z)*ht;
      outp[(size_t)row*128 + colv] = ov;
      if(y2out){
        float dv = dinv[row];
        unsigned pk = __builtin_amdgcn_cvt_pk_fp8_f32(dv*ov, dv*ov, 0, false);
        y2out[(size_t)row*256 + colv] = (unsigned char)(pk & 0xff);
        float hv = dv * hnext[(size_t)row*128 + colv];
        unsigned ph = __builtin_amdgcn_cvt_pk_fp8_f32(hv, hv, 0, false);
        y2out[(size_t)row*256 + 128 + colv] = (unsigned char)(ph & 0xff);
      }
    }
  }
}

extern "C" void kernel_launch(void* const* d_in, const int* in_sizes, int n_in,
                              void* d_out, int out_size, void* d_ws, size_t ws_size,
                              hipStream_t stream){
  const float* x  = (const float*)d_in[0];
  const int*   ei = (const int*)d_in[1];
  const float* h  = (const float*)d_in[2];
  const float* Wx = (const float*)d_in[3];
  const float* bx = (const float*)d_in[4];
  const float* Wh = (const float*)d_in[5];
  const float* bh = (const float*)d_in[6];
  float* out = (float*)d_out;

  const int N = in_sizes[0] / 128;
  const int E = in_sizes[1] / 2;
  const int L = in_sizes[2] / in_sizes[0];
  const int* src = ei;
  const int* dst = ei + E;

  char* w = (char*)d_ws;
  auto alloc = [&](size_t b)->char*{ char* p = w; w += (b + 255) & ~(size_t)255; return p; };
  int* cnt = (int*)alloc((size_t)N*sizeof(int));
  unsigned short* col = (unsigned short*)alloc((size_t)N*CAP*sizeof(short));
  float* dinv = (float*)alloc((size_t)N*sizeof(float));
  unsigned short* WT = (unsigned short*)alloc((size_t)6*32768*sizeof(short));
  unsigned char* y2 = (unsigned char*)alloc((size_t)N*256);
  unsigned short* axah = (unsigned short*)alloc((size_t)N*256*sizeof(short));
  unsigned char* yq = (unsigned char*)alloc((size_t)N*128);
  unsigned short* aq = (unsigned short*)alloc((size_t)N*128*sizeof(short));
  unsigned short* Zbh = (unsigned short*)alloc((size_t)N*128*sizeof(short));
  unsigned* ebuf = (unsigned*)alloc((size_t)NRG*NBB*SEGC*sizeof(unsigned));
  int* cnt2 = (int*)alloc((size_t)NRG*NBB*sizeof(int));

  const int gN = (N + 255)/256;
  const int gew = (N*32 + 255)/256;
  const int g128 = (N + 127)/128;
  const int gagg4 = (N + 15)/16;
  const int gagg2 = (N + 31)/32;

  k_bucket<<<NBB,256,0,stream>>>(src, dst, ebuf, cnt2, E, N);
  k_build2<<<NRG,256,0,stream>>>(ebuf, cnt2, cnt, col, N);
  k_setup<<<gN + 768,256,0,stream>>>(cnt, dinv, N, Wx, Wh, WT);

  for(int l=0; l<L; ++l){
    const float* hl  = h + (size_t)l*N*128;
    const float* bxz = bx + (size_t)(l*3+0)*128; const float* bhz = bh + (size_t)(l*3+0)*128;
    const float* bxr = bx + (size_t)(l*3+1)*128; const float* bhr = bh + (size_t)(l*3+1)*128;
    const float* bxh = bx + (size_t)(l*3+2)*128; const float* bhh = bh + (size_t)(l*3+2)*128;
    const unsigned short* Wz = WT + (size_t)(l*3+0)*32768;
    const unsigned short* Wr = WT + (size_t)(l*3+1)*32768;
    const unsigned short* Wh2= WT + (size_t)(l*3+2)*32768;

    if(l==0) k_scale2<<<gew,256,0,stream>>>(x, hl, dinv, y2, N);
    k_agg<256><<<gagg4,256,0,stream>>>(y2, cnt, col, dinv, axah, N);
    k_gemmRH<<<g128,512,0,stream>>>(axah, Wr, Wh2, hl, dinv, bxr, bhr, yq, Zbh, N);
    k_agg<128><<<gagg2,256,0,stream>>>(yq, cnt, col, dinv, aq, N);
    k_gemmZF<<<g128,512,0,stream>>>(axah, aq, Wz, Wh2, Zbh, hl,
        (l+1<L) ? (h + (size_t)(l+1)*N*128) : nullptr, dinv,
        bxz, bhz, bxh, bhh, out + (size_t)l*N*128,
        (l+1<L) ? y2 : nullptr, N);
  }
}